// Round 1
// baseline (30.196 us; speedup 1.0000x reference)
//
#include <hip/hip_runtime.h>

// Problem constants (match reference)
#define BATCH    128
#define NEV      16
#define NS       32768
#define STEP     256
// Each block computes 1024 output samples (256 threads x float4)
#define TILE     1024

__global__ __launch_bounds__(256)
void summarizer_gather_kernel(const float* __restrict__ x,
                              const int* __restrict__ idx,
                              float* __restrict__ out)
{
    const int tiles_per_batch = NS / TILE;            // 32
    const int tile = blockIdx.x % tiles_per_batch;
    const int b    = blockIdx.x / tiles_per_batch;

    // 16 event start offsets for this batch, staged in LDS (broadcast reads)
    __shared__ int starts[NEV];
    if (threadIdx.x < NEV) {
        starts[threadIdx.x] = idx[b * NEV + threadIdx.x] * STEP;
    }
    __syncthreads();

    // This thread's 4 contiguous output samples.
    // A wave (64 lanes) covers 256 contiguous, 256-aligned samples, and every
    // start s is a multiple of 256 -> (t >= s) is wave-uniform (no divergence).
    const int t = tile * TILE + (int)threadIdx.x * 4;

    const float* xb = x + (size_t)b * NEV * NS;

    float4 acc = make_float4(0.f, 0.f, 0.f, 0.f);
    #pragma unroll
    for (int i = 0; i < NEV; ++i) {
        const int s = starts[i];
        if (t >= s) {
            const float4 v = *reinterpret_cast<const float4*>(
                xb + (size_t)i * NS + (t - s));
            acc.x += v.x;
            acc.y += v.y;
            acc.z += v.z;
            acc.w += v.w;
        }
    }

    *reinterpret_cast<float4*>(out + (size_t)b * NS + t) = acc;
}

extern "C" void kernel_launch(void* const* d_in, const int* in_sizes, int n_in,
                              void* d_out, int out_size, void* d_ws, size_t ws_size,
                              hipStream_t stream)
{
    const float* x   = (const float*)d_in[0];   // [128, 16, 32768] f32
    const int*   idx = (const int*)d_in[1];     // [128, 16] int (harness converts int64 -> int32)
    float*       out = (float*)d_out;           // [128, 1, 32768] f32

    const int grid = BATCH * (NS / TILE);       // 128 * 32 = 4096 blocks
    summarizer_gather_kernel<<<grid, 256, 0, stream>>>(x, idx, out);
}

// Round 2
// 27.822 us; speedup vs baseline: 1.0853x; 1.0853x over previous
//
#include <hip/hip_runtime.h>

// Problem constants (match reference)
#define BATCH    128
#define NEV      16
#define NS       32768
#define STEP     256
#define TILE     1024                 // floats per tile (256 threads x float4)
#define NTILES   (NS / TILE)          // 32 tiles per batch
#define NPAIR    (NTILES / 2)         // 16 tile-pairs per batch

// Each block computes TWO output tiles: j and (31-j). An event with start s
// passes the (t >= s) test for a late tile roughly when it fails for the
// early one, so total load volume per block is ~constant (no straggler tail).
__global__ __launch_bounds__(256)
void summarizer_gather_kernel(const float* __restrict__ x,
                              const int* __restrict__ idx,
                              float* __restrict__ out)
{
    const int p = blockIdx.x % NPAIR;        // tile pair 0..15
    const int b = blockIdx.x / NPAIR;        // batch

    const int tA = p * TILE + (int)threadIdx.x * 4;                  // early tile
    const int tB = (NTILES - 1 - p) * TILE + (int)threadIdx.x * 4;   // late tile

    const float* xb = x + (size_t)b * NEV * NS;
    const int*   ib = idx + b * NEV;         // block-uniform address -> s_load

    float4 accA = make_float4(0.f, 0.f, 0.f, 0.f);
    float4 accB = make_float4(0.f, 0.f, 0.f, 0.f);

    // Every start s is a multiple of 256 and each wave's 64 lanes x float4
    // cover exactly 256 contiguous 256-aligned samples -> (t >= s) is
    // wave-uniform: skipped loads cost zero bandwidth, no divergence.
    #pragma unroll
    for (int i = 0; i < NEV; ++i) {
        const int s = ib[i] * STEP;
        if (tA >= s) {
            const float4 v = *reinterpret_cast<const float4*>(
                xb + (size_t)i * NS + (tA - s));
            accA.x += v.x; accA.y += v.y; accA.z += v.z; accA.w += v.w;
        }
        if (tB >= s) {
            const float4 v = *reinterpret_cast<const float4*>(
                xb + (size_t)i * NS + (tB - s));
            accB.x += v.x; accB.y += v.y; accB.z += v.z; accB.w += v.w;
        }
    }

    float* ob = out + (size_t)b * NS;
    *reinterpret_cast<float4*>(ob + tA) = accA;
    *reinterpret_cast<float4*>(ob + tB) = accB;
}

extern "C" void kernel_launch(void* const* d_in, const int* in_sizes, int n_in,
                              void* d_out, int out_size, void* d_ws, size_t ws_size,
                              hipStream_t stream)
{
    const float* x   = (const float*)d_in[0];   // [128, 16, 32768] f32
    const int*   idx = (const int*)d_in[1];     // [128, 16] int32
    float*       out = (float*)d_out;           // [128, 1, 32768] f32

    const int grid = BATCH * NPAIR;             // 128 * 16 = 2048 blocks
    summarizer_gather_kernel<<<grid, 256, 0, stream>>>(x, idx, out);
}